// Round 12
// baseline (829.937 us; speedup 1.0000x reference)
//
#include <hip/hip_runtime.h>
#include <math.h>

#define N_NODES 50000
#define N_EDGES 800000
#define HID 128
#define H2 256
#define STEPS 12
#define DT 0.5f

#define NB ((N_NODES + 255) / 256)             // 196
#define NODE_BLOCKS ((N_NODES + 31) / 32)      // 1563
#define N_PAD (NODE_BLOCKS * 32)               // 50016
#define CSR_CAP (N_EDGES + 8 * N_NODES)        // 1,200,000 (pad-to-8 worst case)

typedef __attribute__((ext_vector_type(8))) short bf16x8;
typedef __attribute__((ext_vector_type(4))) float f32x4;

__device__ inline unsigned short f2bf(float x) {
    unsigned int u = __float_as_uint(x);
    unsigned int r = (u + 0x7FFFu + ((u >> 16) & 1u)) >> 16;  // round-nearest-even
    return (unsigned short)r;
}
__device__ inline float bf2f(unsigned short b) {
    return __uint_as_float(((unsigned int)b) << 16);
}
__device__ inline float u2f(unsigned int u) { return __uint_as_float(u); }

// fast tanh: tanh(x) = 1 - 2/(e^{2x}+1), via v_exp_f32 (2^x) + v_rcp_f32. err ~1e-7.
__device__ inline float fast_tanh(float x) {
    float xc = fminf(fmaxf(x, -9.0f), 9.0f);
    float t = __builtin_amdgcn_exp2f(xc * 2.8853900817779268f);  // 2/ln2
    return 1.0f - 2.0f * __builtin_amdgcn_rcpf(t + 1.0f);
}

// exact-GELU via Abramowitz-Stegun 7.1.26 erf (max abs err 1.5e-7, branch-free)
__device__ inline float fast_gelu(float x) {
    float u  = x * 0.70710678118654752f;
    float au = fabsf(u);
    float t  = __builtin_amdgcn_rcpf(fmaf(0.3275911f, au, 1.0f));
    float poly = t * (0.254829592f + t * (-0.284496736f + t * (1.421413741f +
                 t * (-1.453152027f + t * 1.061405429f))));
    float ex = __builtin_amdgcn_exp2f(-au * au * 1.4426950408889634f);  // e^{-u^2}
    float erfv = copysignf(1.0f - poly * ex, u);
    return 0.5f * x * (1.0f + erfv);
}

// ---------------- fused init: counts, gcur, pad rows, weight pack ----------------

__global__ void k_init(int* __restrict__ counts, int* __restrict__ gcur,
                       unsigned short* __restrict__ a, unsigned short* __restrict__ b,
                       const float* __restrict__ W1, const float* __restrict__ W2,
                       const float* __restrict__ Win,
                       unsigned short* __restrict__ w1h, unsigned short* __restrict__ w2h,
                       unsigned short* __restrict__ winh) {
    int i = blockIdx.x * 256 + threadIdx.x;
    if (i == 0) *gcur = 0;
    if (i < N_NODES) counts[i] = 0;
    if (i < (N_PAD - N_NODES) * HID) {
        a[(size_t)N_NODES * HID + i] = 0;
        b[(size_t)N_NODES * HID + i] = 0;
    }
    // weight pack: tiles 0..159 (threads 0..10239), single bf16 (hi) plane
    int tile = i >> 6, l = i & 63;
    if (tile < 160) {
        const float* W; unsigned short* out; int K, N, ti;
        if (tile < 64)       { W = W1;  out = w1h;  K = 128; N = 256; ti = tile; }
        else if (tile < 128) { W = W2;  out = w2h;  K = 256; N = 128; ti = tile - 64; }
        else                 { W = Win; out = winh; K = 128; N = 128; ti = tile - 128; }
        int KT = K >> 5;
        int kt = ti % KT, nt = ti / KT;
        int n  = nt * 16 + (l & 15);
        int k0 = kt * 32 + (l >> 4) * 8;
        int base = ((nt * KT + kt) * 64 + l) * 8;
        for (int j = 0; j < 8; j++)
            out[base + j] = f2bf(W[(size_t)(k0 + j) * N + n]);
    }
}

__global__ void k_hist(const int* __restrict__ dst, int* __restrict__ counts) {
    int e = blockIdx.x * 256 + threadIdx.x;
    if (e < N_EDGES) atomicAdd(&counts[dst[e]], 1);
}

// segment placement via global cursor (ordering proven perf-neutral, R3==R4).
// Also writes the dummy pad slots (<=7 per node).
__global__ void k_offsets_atomic(const int* __restrict__ counts, int* __restrict__ gcur,
                                 int* __restrict__ offsets, int* __restrict__ cursor,
                                 int* __restrict__ csr_src) {
    int i = blockIdx.x * 256 + threadIdx.x;
    if (i < N_NODES) {
        int d = counts[i];
        int p = (d + 7) & ~7;
        int o = atomicAdd(gcur, p);
        offsets[i] = o;
        cursor[i]  = o;
        for (int j = d; j < p; j++) csr_src[o + j] = N_NODES;  // dummy -> zeroed pad row
    }
}

__global__ void k_scatter(const int* __restrict__ src, const int* __restrict__ dst,
                          int* __restrict__ cursor, int* __restrict__ csr_src) {
    int e = blockIdx.x * 256 + threadIdx.x;
    if (e < N_EDGES) {
        int d = dst[e];
        int p = atomicAdd(&cursor[d], 1);
        csr_src[p] = src[e];
    }
}

// ---------------- h0 = tanh(gat @ W_in + b_in), MFMA (A hi/lo x W bf16) ----------------

__global__ __launch_bounds__(256, 3) void k_h0_mfma(
    const float* __restrict__ gat,
    const unsigned short* __restrict__ wh,
    const float* __restrict__ b_in, float* __restrict__ h,
    unsigned short* __restrict__ hbf) {
    __shared__ unsigned short Ahi[32][136];
    __shared__ unsigned short Alo[32][136];
    int tid = threadIdx.x;
    int node0 = blockIdx.x * 32;

    for (int idx = tid; idx < 32 * 64; idx += 256) {
        int m = idx >> 6, c = (idx & 63) * 2;
        float2 v;
        if (node0 + m < N_NODES) v = *(const float2*)&gat[(size_t)(node0 + m) * 128 + c];
        else { v.x = 0.f; v.y = 0.f; }
        unsigned short h0 = f2bf(v.x), h1 = f2bf(v.y);
        unsigned short l0 = f2bf(v.x - bf2f(h0)), l1 = f2bf(v.y - bf2f(h1));
        *(unsigned int*)&Ahi[m][c] = (unsigned int)h0 | ((unsigned int)h1 << 16);
        *(unsigned int*)&Alo[m][c] = (unsigned int)l0 | ((unsigned int)l1 << 16);
    }
    __syncthreads();

    int l = tid & 63, wv = tid >> 6;
    int c15 = l & 15, q = l >> 4;
    f32x4 acc[2][2] = {};
#pragma unroll
    for (int kt = 0; kt < 4; kt++) {
        bf16x8 ah[2], al[2];
#pragma unroll
        for (int mt = 0; mt < 2; mt++) {
            ah[mt] = *(const bf16x8*)&Ahi[mt * 16 + c15][kt * 32 + q * 8];
            al[mt] = *(const bf16x8*)&Alo[mt * 16 + c15][kt * 32 + q * 8];
        }
#pragma unroll
        for (int nn = 0; nn < 2; nn++) {
            int nt = wv * 2 + nn;
            bf16x8 bh = *(const bf16x8*)&wh[(size_t)((nt * 4 + kt) * 64 + l) * 8];
#pragma unroll
            for (int mt = 0; mt < 2; mt++) {
                acc[mt][nn] = __builtin_amdgcn_mfma_f32_16x16x32_bf16(ah[mt], bh, acc[mt][nn], 0, 0, 0);
                acc[mt][nn] = __builtin_amdgcn_mfma_f32_16x16x32_bf16(al[mt], bh, acc[mt][nn], 0, 0, 0);
            }
        }
    }
#pragma unroll
    for (int nn = 0; nn < 2; nn++) {
        int col = (wv * 2 + nn) * 16 + c15;
        float bb = b_in[col];
#pragma unroll
        for (int mt = 0; mt < 2; mt++)
#pragma unroll
            for (int r = 0; r < 4; r++) {
                int node = node0 + mt * 16 + q * 4 + r;
                if (node < N_NODES) {
                    float v = fast_tanh(acc[mt][nn][r] + bb);
                    h[(size_t)node * 128 + col]   = v;
                    hbf[(size_t)node * 128 + col] = f2bf(v);
                }
            }
    }
}

// ---------------- fused step, 1024 threads / 16 waves, M=32 ----------------
// Round-12: lane-parallel gather split. Each node's edge list is split across
// TWO 16-lane groups (even/odd 8-edge chunks); one __shfl_xor(,16) merges.
// The per-node serial chunk chain HALVES — and unlike R5/R8 (ILP within a
// thread, which the compiler serialized to protect VGPR), lane parallelism
// cannot be serialized and costs no registers. Parity groups write hi/lo
// planes respectively. 16 waves: GEMM1 1 nt/wave, GEMM2 1 nt x 1 mt/wave.
// Occupancy: 2 blocks/CU x 16 waves = 32 waves/CU (same as R7's 4x8).

#define ACC8(V) \
    a0 += u2f((V).x << 16); a1 += u2f((V).x & 0xFFFF0000u); \
    a2 += u2f((V).y << 16); a3 += u2f((V).y & 0xFFFF0000u); \
    a4 += u2f((V).z << 16); a5 += u2f((V).z & 0xFFFF0000u); \
    a6 += u2f((V).w << 16); a7 += u2f((V).w & 0xFFFF0000u);

__global__ __launch_bounds__(1024, 8) void k_step(
    const unsigned short* __restrict__ hbf_in,
    float* __restrict__ h, unsigned short* __restrict__ hbf_out,
    const int* __restrict__ offsets, const int* __restrict__ csr,
    const int* __restrict__ cnt,
    const unsigned short* __restrict__ w1h,
    const float* __restrict__ b1,
    const unsigned short* __restrict__ w2h,
    const float* __restrict__ b2, const float* __restrict__ clr) {
    __shared__ unsigned short Ahi[32][136];
    __shared__ unsigned short Alo[32][136];
    __shared__ unsigned short Y[32][264];
    int tid = threadIdx.x, l = tid & 63, wv = tid >> 6;   // wv 0..15
    int c15 = l & 15, q = l >> 4;
    int node0 = blockIdx.x * 32;
    int g  = l >> 4;       // group-within-wave 0..3
    int cl = l & 15;       // col chunk: cols cl*8..+8

    // ---- Phase 1: segment-mean gather, TWO 16-lane groups per node ----
    {
        int gg = wv * 4 + g;           // global group 0..63
        int m  = gg >> 1;              // node row 0..31
        int p  = gg & 1;               // chunk parity
        int node = node0 + m;
        float a0 = 0.f, a1 = 0.f, a2 = 0.f, a3 = 0.f;
        float a4 = 0.f, a5 = 0.f, a6 = 0.f, a7 = 0.f;
        int deg = 0;
        if (node < N_NODES) {
            deg = cnt[node];
            int beg = offsets[node];
            int end = beg + ((deg + 7) & ~7);         // padded, %8 == 0
            const unsigned short* hb = hbf_in + cl * 8;
            int e = beg + p * 8;                      // this group's first chunk
            if (e < end) {
                int4 i0 = *(const int4*)&csr[e];
                int4 i1 = *(const int4*)&csr[e + 4];
                for (; e < end; e += 16) {
                    int enx = (e + 16 < end) ? (e + 16) : e;
                    int4 j0 = *(const int4*)&csr[enx];
                    int4 j1 = *(const int4*)&csr[enx + 4];
                    uint4 w0 = *(const uint4*)&hb[((unsigned)i0.x) << 7];
                    uint4 w1 = *(const uint4*)&hb[((unsigned)i0.y) << 7];
                    uint4 w2 = *(const uint4*)&hb[((unsigned)i0.z) << 7];
                    uint4 w3 = *(const uint4*)&hb[((unsigned)i0.w) << 7];
                    uint4 w4 = *(const uint4*)&hb[((unsigned)i1.x) << 7];
                    uint4 w5 = *(const uint4*)&hb[((unsigned)i1.y) << 7];
                    uint4 w6 = *(const uint4*)&hb[((unsigned)i1.z) << 7];
                    uint4 w7 = *(const uint4*)&hb[((unsigned)i1.w) << 7];
                    i0 = j0; i1 = j1;
                    ACC8(w0); ACC8(w1); ACC8(w2); ACC8(w3);
                    ACC8(w4); ACC8(w5); ACC8(w6); ACC8(w7);
                }
            }
        }
        // merge even/odd partial sums across the 16-lane parity pair
        a0 += __shfl_xor(a0, 16); a1 += __shfl_xor(a1, 16);
        a2 += __shfl_xor(a2, 16); a3 += __shfl_xor(a3, 16);
        a4 += __shfl_xor(a4, 16); a5 += __shfl_xor(a5, 16);
        a6 += __shfl_xor(a6, 16); a7 += __shfl_xor(a7, 16);

        float inv = (deg > 1) ? 1.0f / (float)deg : 1.0f;
        float x0 = a0 * inv, x1 = a1 * inv, x2 = a2 * inv, x3 = a3 * inv;
        float x4 = a4 * inv, x5 = a5 * inv, x6 = a6 * inv, x7 = a7 * inv;
        unsigned short h0 = f2bf(x0), h1 = f2bf(x1), h2 = f2bf(x2), h3 = f2bf(x3);
        unsigned short h4 = f2bf(x4), h5 = f2bf(x5), h6 = f2bf(x6), h7 = f2bf(x7);
        if (p == 0) {
            uint4 o;
            o.x = (unsigned int)h0 | ((unsigned int)h1 << 16);
            o.y = (unsigned int)h2 | ((unsigned int)h3 << 16);
            o.z = (unsigned int)h4 | ((unsigned int)h5 << 16);
            o.w = (unsigned int)h6 | ((unsigned int)h7 << 16);
            *(uint4*)&Ahi[m][cl * 8] = o;
        } else {
            unsigned short l0 = f2bf(x0 - bf2f(h0)), l1 = f2bf(x1 - bf2f(h1));
            unsigned short l2 = f2bf(x2 - bf2f(h2)), l3 = f2bf(x3 - bf2f(h3));
            unsigned short l4 = f2bf(x4 - bf2f(h4)), l5 = f2bf(x5 - bf2f(h5));
            unsigned short l6 = f2bf(x6 - bf2f(h6)), l7 = f2bf(x7 - bf2f(h7));
            uint4 o;
            o.x = (unsigned int)l0 | ((unsigned int)l1 << 16);
            o.y = (unsigned int)l2 | ((unsigned int)l3 << 16);
            o.z = (unsigned int)l4 | ((unsigned int)l5 << 16);
            o.w = (unsigned int)l6 | ((unsigned int)l7 << 16);
            *(uint4*)&Alo[m][cl * 8] = o;
        }
    }
    __syncthreads();

    // ---- Phase 2: GEMM1 [32x128]@[128x256], 2-product, 1 nt/wave (16 waves) ----
    {
        f32x4 acc1[2] = {};   // [mt]
#pragma unroll
        for (int kt = 0; kt < 4; kt++) {
            bf16x8 ah[2], al[2];
#pragma unroll
            for (int mt = 0; mt < 2; mt++) {
                ah[mt] = *(const bf16x8*)&Ahi[mt * 16 + c15][kt * 32 + q * 8];
                al[mt] = *(const bf16x8*)&Alo[mt * 16 + c15][kt * 32 + q * 8];
            }
            bf16x8 bh = *(const bf16x8*)&w1h[(size_t)((wv * 4 + kt) * 64 + l) * 8];
#pragma unroll
            for (int mt = 0; mt < 2; mt++) {
                acc1[mt] = __builtin_amdgcn_mfma_f32_16x16x32_bf16(ah[mt], bh, acc1[mt], 0, 0, 0);
                acc1[mt] = __builtin_amdgcn_mfma_f32_16x16x32_bf16(al[mt], bh, acc1[mt], 0, 0, 0);
            }
        }
        int col = wv * 16 + c15;
        float bb = b1[col];
#pragma unroll
        for (int mt = 0; mt < 2; mt++)
#pragma unroll
            for (int r = 0; r < 4; r++) {
                int row = mt * 16 + q * 4 + r;
                float x = acc1[mt][r] + bb;
                Y[row][col] = f2bf(fast_gelu(x));
            }
    }
    __syncthreads();

    // ---- Phase 3: GEMM2 [32x256]@[256x128], 1-product, 1 nt x 1 mt / wave ----
    {
        int nt2 = wv >> 1, mt2 = wv & 1;
        f32x4 acc2 = {};
#pragma unroll
        for (int kt = 0; kt < 8; kt++) {
            bf16x8 ya = *(const bf16x8*)&Y[mt2 * 16 + c15][kt * 32 + q * 8];
            bf16x8 bh = *(const bf16x8*)&w2h[(size_t)((nt2 * 8 + kt) * 64 + l) * 8];
            acc2 = __builtin_amdgcn_mfma_f32_16x16x32_bf16(ya, bh, acc2, 0, 0, 0);
        }
        float decay = fmaxf(clr[0], 0.0f);
        int col = nt2 * 16 + c15;
        float bb = b2[col];
#pragma unroll
        for (int r = 0; r < 4; r++) {
            int node = node0 + mt2 * 16 + q * 4 + r;
            if (node < N_NODES) {
                float hv = h[(size_t)node * 128 + col];
                float diff = fast_tanh(acc2[r] + bb);
                float nh = hv + (diff - decay * hv) * DT;
                h[(size_t)node * 128 + col]       = nh;
                hbf_out[(size_t)node * 128 + col] = f2bf(nh);
            }
        }
    }
}

// ---------------- launch ----------------

extern "C" void kernel_launch(void* const* d_in, const int* in_sizes, int n_in,
                              void* d_out, int out_size, void* d_ws, size_t ws_size,
                              hipStream_t stream) {
    const float* gat   = (const float*)d_in[0];
    const int*   edges = (const int*)d_in[1];     // [2, E]: row0 = src, row1 = dst
    const float* W_in  = (const float*)d_in[2];
    const float* b_in  = (const float*)d_in[3];
    const float* W1    = (const float*)d_in[4];
    const float* b1    = (const float*)d_in[5];
    const float* W2    = (const float*)d_in[6];
    const float* b2    = (const float*)d_in[7];
    const float* clr   = (const float*)d_in[8];
    float* h = (float*)d_out;

    const int* src = edges;
    const int* dst = edges + N_EDGES;

    char* ws = (char*)d_ws;
    size_t off = 0;
    auto alloc = [&](size_t bytes) -> void* {
        off = (off + 255) & ~(size_t)255;
        void* p = ws + off;
        off += bytes;
        return p;
    };
    int*   counts  = (int*)alloc(sizeof(int) * N_NODES);
    int*   offsets = (int*)alloc(sizeof(int) * N_NODES);
    int*   cursor  = (int*)alloc(sizeof(int) * N_NODES);
    int*   gcur    = (int*)alloc(sizeof(int));
    int*   csr_src = (int*)alloc(sizeof(int) * CSR_CAP);
    unsigned short* hbfA = (unsigned short*)alloc(sizeof(short) * (size_t)N_PAD * HID);
    unsigned short* hbfB = (unsigned short*)alloc(sizeof(short) * (size_t)N_PAD * HID);
    unsigned short* w1h  = (unsigned short*)alloc(sizeof(short) * HID * H2);
    unsigned short* w2h  = (unsigned short*)alloc(sizeof(short) * H2 * HID);
    unsigned short* winh = (unsigned short*)alloc(sizeof(short) * HID * HID);

    // fused init: counts, gcur, pad rows, weight pack
    k_init<<<NB, 256, 0, stream>>>(counts, gcur, hbfA, hbfB,
                                   W1, W2, W_in, w1h, w2h, winh);
    k_hist<<<(N_EDGES + 255) / 256, 256, 0, stream>>>(dst, counts);
    k_offsets_atomic<<<NB, 256, 0, stream>>>(counts, gcur, offsets, cursor, csr_src);
    k_scatter<<<(N_EDGES + 255) / 256, 256, 0, stream>>>(src, dst, cursor, csr_src);

    // h0 (writes f32 h and bf16 hbfA)
    k_h0_mfma<<<NODE_BLOCKS, 256, 0, stream>>>(gat, winh, b_in, h, hbfA);

    // 12 fused Euler steps; bf16 state ping-pongs, f32 h in place
    for (int s = 0; s < STEPS; s++) {
        const unsigned short* in = (s & 1) ? hbfB : hbfA;
        unsigned short*      out = (s & 1) ? hbfA : hbfB;
        k_step<<<NODE_BLOCKS, 1024, 0, stream>>>(in, h, out, offsets, csr_src, counts,
                                                 w1h, b1, w2h, b2, clr);
    }
}

// Round 13
// 768.816 us; speedup vs baseline: 1.0795x; 1.0795x over previous
//
#include <hip/hip_runtime.h>
#include <math.h>

#define N_NODES 50000
#define N_EDGES 800000
#define HID 128
#define H2 256
#define STEPS 12
#define DT 0.5f

#define NB ((N_NODES + 255) / 256)             // 196
#define NODE_BLOCKS ((N_NODES + 31) / 32)      // 1563
#define N_PAD (NODE_BLOCKS * 32)               // 50016
#define CSR_CAP (N_EDGES + 8 * N_NODES)        // 1,200,000 (pad-to-8 worst case)

typedef __attribute__((ext_vector_type(8))) short bf16x8;
typedef __attribute__((ext_vector_type(4))) float f32x4;

__device__ inline unsigned short f2bf(float x) {
    unsigned int u = __float_as_uint(x);
    unsigned int r = (u + 0x7FFFu + ((u >> 16) & 1u)) >> 16;  // round-nearest-even
    return (unsigned short)r;
}
__device__ inline float bf2f(unsigned short b) {
    return __uint_as_float(((unsigned int)b) << 16);
}
__device__ inline float u2f(unsigned int u) { return __uint_as_float(u); }

// fast tanh: tanh(x) = 1 - 2/(e^{2x}+1), via v_exp_f32 (2^x) + v_rcp_f32. err ~1e-7.
__device__ inline float fast_tanh(float x) {
    float xc = fminf(fmaxf(x, -9.0f), 9.0f);
    float t = __builtin_amdgcn_exp2f(xc * 2.8853900817779268f);  // 2/ln2
    return 1.0f - 2.0f * __builtin_amdgcn_rcpf(t + 1.0f);
}

// exact-GELU via Abramowitz-Stegun 7.1.26 erf (max abs err 1.5e-7, branch-free)
__device__ inline float fast_gelu(float x) {
    float u  = x * 0.70710678118654752f;
    float au = fabsf(u);
    float t  = __builtin_amdgcn_rcpf(fmaf(0.3275911f, au, 1.0f));
    float poly = t * (0.254829592f + t * (-0.284496736f + t * (1.421413741f +
                 t * (-1.453152027f + t * 1.061405429f))));
    float ex = __builtin_amdgcn_exp2f(-au * au * 1.4426950408889634f);  // e^{-u^2}
    float erfv = copysignf(1.0f - poly * ex, u);
    return 0.5f * x * (1.0f + erfv);
}

// ---------------- fused init: counts, gcur, pad rows, weight pack ----------------

__global__ void k_init(int* __restrict__ counts, int* __restrict__ gcur,
                       unsigned short* __restrict__ a, unsigned short* __restrict__ b,
                       const float* __restrict__ W1, const float* __restrict__ W2,
                       const float* __restrict__ Win,
                       unsigned short* __restrict__ w1h, unsigned short* __restrict__ w2h,
                       unsigned short* __restrict__ winh) {
    int i = blockIdx.x * 256 + threadIdx.x;
    if (i == 0) *gcur = 0;
    if (i < N_NODES) counts[i] = 0;
    if (i < (N_PAD - N_NODES) * HID) {
        a[(size_t)N_NODES * HID + i] = 0;
        b[(size_t)N_NODES * HID + i] = 0;
    }
    // weight pack: tiles 0..159 (threads 0..10239), single bf16 (hi) plane
    int tile = i >> 6, l = i & 63;
    if (tile < 160) {
        const float* W; unsigned short* out; int K, N, ti;
        if (tile < 64)       { W = W1;  out = w1h;  K = 128; N = 256; ti = tile; }
        else if (tile < 128) { W = W2;  out = w2h;  K = 256; N = 128; ti = tile - 64; }
        else                 { W = Win; out = winh; K = 128; N = 128; ti = tile - 128; }
        int KT = K >> 5;
        int kt = ti % KT, nt = ti / KT;
        int n  = nt * 16 + (l & 15);
        int k0 = kt * 32 + (l >> 4) * 8;
        int base = ((nt * KT + kt) * 64 + l) * 8;
        for (int j = 0; j < 8; j++)
            out[base + j] = f2bf(W[(size_t)(k0 + j) * N + n]);
    }
}

__global__ void k_hist(const int* __restrict__ dst, int* __restrict__ counts) {
    int e = blockIdx.x * 256 + threadIdx.x;
    if (e < N_EDGES) atomicAdd(&counts[dst[e]], 1);
}

// segment placement via global cursor (ordering proven perf-neutral, R3==R4).
// Also writes the dummy pad slots (<=7 per node).
__global__ void k_offsets_atomic(const int* __restrict__ counts, int* __restrict__ gcur,
                                 int* __restrict__ offsets, int* __restrict__ cursor,
                                 int* __restrict__ csr_src) {
    int i = blockIdx.x * 256 + threadIdx.x;
    if (i < N_NODES) {
        int d = counts[i];
        int p = (d + 7) & ~7;
        int o = atomicAdd(gcur, p);
        offsets[i] = o;
        cursor[i]  = o;
        for (int j = d; j < p; j++) csr_src[o + j] = N_NODES;  // dummy -> zeroed pad row
    }
}

__global__ void k_scatter(const int* __restrict__ src, const int* __restrict__ dst,
                          int* __restrict__ cursor, int* __restrict__ csr_src) {
    int e = blockIdx.x * 256 + threadIdx.x;
    if (e < N_EDGES) {
        int d = dst[e];
        int p = atomicAdd(&cursor[d], 1);
        csr_src[p] = src[e];
    }
}

// ---------------- h0 = tanh(gat @ W_in + b_in), MFMA (A hi/lo x W bf16) ----------------

__global__ __launch_bounds__(256, 3) void k_h0_mfma(
    const float* __restrict__ gat,
    const unsigned short* __restrict__ wh,
    const float* __restrict__ b_in, float* __restrict__ h,
    unsigned short* __restrict__ hbf) {
    __shared__ unsigned short Ahi[32][136];
    __shared__ unsigned short Alo[32][136];
    int tid = threadIdx.x;
    int node0 = blockIdx.x * 32;

    for (int idx = tid; idx < 32 * 64; idx += 256) {
        int m = idx >> 6, c = (idx & 63) * 2;
        float2 v;
        if (node0 + m < N_NODES) v = *(const float2*)&gat[(size_t)(node0 + m) * 128 + c];
        else { v.x = 0.f; v.y = 0.f; }
        unsigned short h0 = f2bf(v.x), h1 = f2bf(v.y);
        unsigned short l0 = f2bf(v.x - bf2f(h0)), l1 = f2bf(v.y - bf2f(h1));
        *(unsigned int*)&Ahi[m][c] = (unsigned int)h0 | ((unsigned int)h1 << 16);
        *(unsigned int*)&Alo[m][c] = (unsigned int)l0 | ((unsigned int)l1 << 16);
    }
    __syncthreads();

    int l = tid & 63, wv = tid >> 6;
    int c15 = l & 15, q = l >> 4;
    f32x4 acc[2][2] = {};
#pragma unroll
    for (int kt = 0; kt < 4; kt++) {
        bf16x8 ah[2], al[2];
#pragma unroll
        for (int mt = 0; mt < 2; mt++) {
            ah[mt] = *(const bf16x8*)&Ahi[mt * 16 + c15][kt * 32 + q * 8];
            al[mt] = *(const bf16x8*)&Alo[mt * 16 + c15][kt * 32 + q * 8];
        }
#pragma unroll
        for (int nn = 0; nn < 2; nn++) {
            int nt = wv * 2 + nn;
            bf16x8 bh = *(const bf16x8*)&wh[(size_t)((nt * 4 + kt) * 64 + l) * 8];
#pragma unroll
            for (int mt = 0; mt < 2; mt++) {
                acc[mt][nn] = __builtin_amdgcn_mfma_f32_16x16x32_bf16(ah[mt], bh, acc[mt][nn], 0, 0, 0);
                acc[mt][nn] = __builtin_amdgcn_mfma_f32_16x16x32_bf16(al[mt], bh, acc[mt][nn], 0, 0, 0);
            }
        }
    }
#pragma unroll
    for (int nn = 0; nn < 2; nn++) {
        int col = (wv * 2 + nn) * 16 + c15;
        float bb = b_in[col];
#pragma unroll
        for (int mt = 0; mt < 2; mt++)
#pragma unroll
            for (int r = 0; r < 4; r++) {
                int node = node0 + mt * 16 + q * 4 + r;
                if (node < N_NODES) {
                    float v = fast_tanh(acc[mt][nn][r] + bb);
                    h[(size_t)node * 128 + col]   = v;
                    hbf[(size_t)node * 128 + col] = f2bf(v);
                }
            }
    }
}

// ---------------- fused step, 512 threads / 8 waves, M=32 ----------------
// FINAL (= Round-7/11 body, verified 51.5us x3: R7, R11, this round).
// Refuted escapes (do not reintroduce):
//   R5  wider chunks        -> compiler serializes to protect VGPR (+1.7us only)
//   R6  coop grid.sync      -> L2 flush per step, 2650us
//   R8  asm load pinning    -> VGPR 48, occupancy 34%, +4us
//   R9  persistent tickets  -> VGPR 52, occupancy 36%, +11us
//   R10 degree-rank perm    -> dependent load at chain head, +4us
//   R12 lane-parallel split -> chain halved AND occ up, still +4us (issue/bank-conflict)
// Conclusion: balanced multi-constraint state (VALU ~39%, HBM ~30%, L2 ~400MB/step,
// 2 barriers); every pipe 30-40%, no single bottleneck.

#define ACC8(V) \
    a0 += u2f((V).x << 16); a1 += u2f((V).x & 0xFFFF0000u); \
    a2 += u2f((V).y << 16); a3 += u2f((V).y & 0xFFFF0000u); \
    a4 += u2f((V).z << 16); a5 += u2f((V).z & 0xFFFF0000u); \
    a6 += u2f((V).w << 16); a7 += u2f((V).w & 0xFFFF0000u);

__global__ __launch_bounds__(512, 4) void k_step(
    const unsigned short* __restrict__ hbf_in,
    float* __restrict__ h, unsigned short* __restrict__ hbf_out,
    const int* __restrict__ offsets, const int* __restrict__ csr,
    const int* __restrict__ cnt,
    const unsigned short* __restrict__ w1h,
    const float* __restrict__ b1,
    const unsigned short* __restrict__ w2h,
    const float* __restrict__ b2, const float* __restrict__ clr) {
    __shared__ unsigned short Ahi[32][136];
    __shared__ unsigned short Alo[32][136];
    __shared__ unsigned short Y[32][264];
    int tid = threadIdx.x, l = tid & 63, wv = tid >> 6;   // wv 0..7
    int c15 = l & 15, q = l >> 4;
    int node0 = blockIdx.x * 32;
    int g  = l >> 4;       // node-within-wave 0..3
    int cl = l & 15;       // col chunk: cols cl*8..+8

    // ---- Phase 1: segment-mean gather, one node per 16-lane group ----
    {
        int m = wv * 4 + g;            // 0..31
        int node = node0 + m;
        float a0 = 0.f, a1 = 0.f, a2 = 0.f, a3 = 0.f;
        float a4 = 0.f, a5 = 0.f, a6 = 0.f, a7 = 0.f;
        int deg = 0;
        if (node < N_NODES) {
            deg = cnt[node];
            int beg = offsets[node];
            int end = beg + ((deg + 7) & ~7);         // padded, %8 == 0
            const unsigned short* hb = hbf_in + cl * 8;
            if (beg < end) {
                int4 i0 = *(const int4*)&csr[beg];
                int4 i1 = *(const int4*)&csr[beg + 4];
                for (int e = beg; e < end; e += 8) {
                    int enx = (e + 8 < end) ? (e + 8) : e;
                    int4 j0 = *(const int4*)&csr[enx];
                    int4 j1 = *(const int4*)&csr[enx + 4];
                    uint4 w0 = *(const uint4*)&hb[((unsigned)i0.x) << 7];
                    uint4 w1 = *(const uint4*)&hb[((unsigned)i0.y) << 7];
                    uint4 w2 = *(const uint4*)&hb[((unsigned)i0.z) << 7];
                    uint4 w3 = *(const uint4*)&hb[((unsigned)i0.w) << 7];
                    uint4 w4 = *(const uint4*)&hb[((unsigned)i1.x) << 7];
                    uint4 w5 = *(const uint4*)&hb[((unsigned)i1.y) << 7];
                    uint4 w6 = *(const uint4*)&hb[((unsigned)i1.z) << 7];
                    uint4 w7 = *(const uint4*)&hb[((unsigned)i1.w) << 7];
                    i0 = j0; i1 = j1;
                    ACC8(w0); ACC8(w1); ACC8(w2); ACC8(w3);
                    ACC8(w4); ACC8(w5); ACC8(w6); ACC8(w7);
                }
            }
        }
        float inv = (deg > 1) ? 1.0f / (float)deg : 1.0f;
        float x0 = a0 * inv, x1 = a1 * inv, x2 = a2 * inv, x3 = a3 * inv;
        float x4 = a4 * inv, x5 = a5 * inv, x6 = a6 * inv, x7 = a7 * inv;
        unsigned short h0 = f2bf(x0), h1 = f2bf(x1), h2 = f2bf(x2), h3 = f2bf(x3);
        unsigned short h4 = f2bf(x4), h5 = f2bf(x5), h6 = f2bf(x6), h7 = f2bf(x7);
        uint4 ohi;
        ohi.x = (unsigned int)h0 | ((unsigned int)h1 << 16);
        ohi.y = (unsigned int)h2 | ((unsigned int)h3 << 16);
        ohi.z = (unsigned int)h4 | ((unsigned int)h5 << 16);
        ohi.w = (unsigned int)h6 | ((unsigned int)h7 << 16);
        *(uint4*)&Ahi[m][cl * 8] = ohi;
        unsigned short l0 = f2bf(x0 - bf2f(h0)), l1 = f2bf(x1 - bf2f(h1));
        unsigned short l2 = f2bf(x2 - bf2f(h2)), l3 = f2bf(x3 - bf2f(h3));
        unsigned short l4 = f2bf(x4 - bf2f(h4)), l5 = f2bf(x5 - bf2f(h5));
        unsigned short l6 = f2bf(x6 - bf2f(h6)), l7 = f2bf(x7 - bf2f(h7));
        uint4 olo;
        olo.x = (unsigned int)l0 | ((unsigned int)l1 << 16);
        olo.y = (unsigned int)l2 | ((unsigned int)l3 << 16);
        olo.z = (unsigned int)l4 | ((unsigned int)l5 << 16);
        olo.w = (unsigned int)l6 | ((unsigned int)l7 << 16);
        *(uint4*)&Alo[m][cl * 8] = olo;
    }
    __syncthreads();

    // ---- Phase 2: GEMM1 [32x128]@[128x256], 2-product, 2 nt/wave ----
    {
        f32x4 acc1[2][2] = {};   // [mt][nn]
#pragma unroll
        for (int kt = 0; kt < 4; kt++) {
            bf16x8 ah[2], al[2];
#pragma unroll
            for (int mt = 0; mt < 2; mt++) {
                ah[mt] = *(const bf16x8*)&Ahi[mt * 16 + c15][kt * 32 + q * 8];
                al[mt] = *(const bf16x8*)&Alo[mt * 16 + c15][kt * 32 + q * 8];
            }
#pragma unroll
            for (int nn = 0; nn < 2; nn++) {
                int nt = wv * 2 + nn;
                bf16x8 bh = *(const bf16x8*)&w1h[(size_t)((nt * 4 + kt) * 64 + l) * 8];
#pragma unroll
                for (int mt = 0; mt < 2; mt++) {
                    acc1[mt][nn] = __builtin_amdgcn_mfma_f32_16x16x32_bf16(ah[mt], bh, acc1[mt][nn], 0, 0, 0);
                    acc1[mt][nn] = __builtin_amdgcn_mfma_f32_16x16x32_bf16(al[mt], bh, acc1[mt][nn], 0, 0, 0);
                }
            }
        }
#pragma unroll
        for (int nn = 0; nn < 2; nn++) {
            int col = (wv * 2 + nn) * 16 + c15;
            float bb = b1[col];
#pragma unroll
            for (int mt = 0; mt < 2; mt++)
#pragma unroll
                for (int r = 0; r < 4; r++) {
                    int row = mt * 16 + q * 4 + r;
                    float x = acc1[mt][nn][r] + bb;
                    Y[row][col] = f2bf(fast_gelu(x));
                }
        }
    }
    __syncthreads();

    // ---- Phase 3: GEMM2 [32x256]@[256x128], 1-product, 1 nt/wave ----
    f32x4 acc2[2] = {};   // [mt]
#pragma unroll
    for (int kt = 0; kt < 8; kt++) {
        bf16x8 ya[2];
#pragma unroll
        for (int mt = 0; mt < 2; mt++)
            ya[mt] = *(const bf16x8*)&Y[mt * 16 + c15][kt * 32 + q * 8];
        bf16x8 bh = *(const bf16x8*)&w2h[(size_t)((wv * 8 + kt) * 64 + l) * 8];
#pragma unroll
        for (int mt = 0; mt < 2; mt++)
            acc2[mt] = __builtin_amdgcn_mfma_f32_16x16x32_bf16(ya[mt], bh, acc2[mt], 0, 0, 0);
    }
    float decay = fmaxf(clr[0], 0.0f);
    {
        int col = wv * 16 + c15;
        float bb = b2[col];
#pragma unroll
        for (int mt = 0; mt < 2; mt++)
#pragma unroll
            for (int r = 0; r < 4; r++) {
                int node = node0 + mt * 16 + q * 4 + r;
                if (node < N_NODES) {
                    float hv = h[(size_t)node * 128 + col];
                    float diff = fast_tanh(acc2[mt][r] + bb);
                    float nh = hv + (diff - decay * hv) * DT;
                    h[(size_t)node * 128 + col]       = nh;
                    hbf_out[(size_t)node * 128 + col] = f2bf(nh);
                }
            }
    }
}

// ---------------- launch ----------------

extern "C" void kernel_launch(void* const* d_in, const int* in_sizes, int n_in,
                              void* d_out, int out_size, void* d_ws, size_t ws_size,
                              hipStream_t stream) {
    const float* gat   = (const float*)d_in[0];
    const int*   edges = (const int*)d_in[1];     // [2, E]: row0 = src, row1 = dst
    const float* W_in  = (const float*)d_in[2];
    const float* b_in  = (const float*)d_in[3];
    const float* W1    = (const float*)d_in[4];
    const float* b1    = (const float*)d_in[5];
    const float* W2    = (const float*)d_in[6];
    const float* b2    = (const float*)d_in[7];
    const float* clr   = (const float*)d_in[8];
    float* h = (float*)d_out;

    const int* src = edges;
    const int* dst = edges + N_EDGES;

    char* ws = (char*)d_ws;
    size_t off = 0;
    auto alloc = [&](size_t bytes) -> void* {
        off = (off + 255) & ~(size_t)255;
        void* p = ws + off;
        off += bytes;
        return p;
    };
    int*   counts  = (int*)alloc(sizeof(int) * N_NODES);
    int*   offsets = (int*)alloc(sizeof(int) * N_NODES);
    int*   cursor  = (int*)alloc(sizeof(int) * N_NODES);
    int*   gcur    = (int*)alloc(sizeof(int));
    int*   csr_src = (int*)alloc(sizeof(int) * CSR_CAP);
    unsigned short* hbfA = (unsigned short*)alloc(sizeof(short) * (size_t)N_PAD * HID);
    unsigned short* hbfB = (unsigned short*)alloc(sizeof(short) * (size_t)N_PAD * HID);
    unsigned short* w1h  = (unsigned short*)alloc(sizeof(short) * HID * H2);
    unsigned short* w2h  = (unsigned short*)alloc(sizeof(short) * H2 * HID);
    unsigned short* winh = (unsigned short*)alloc(sizeof(short) * HID * HID);

    // fused init: counts, gcur, pad rows, weight pack
    k_init<<<NB, 256, 0, stream>>>(counts, gcur, hbfA, hbfB,
                                   W1, W2, W_in, w1h, w2h, winh);
    k_hist<<<(N_EDGES + 255) / 256, 256, 0, stream>>>(dst, counts);
    k_offsets_atomic<<<NB, 256, 0, stream>>>(counts, gcur, offsets, cursor, csr_src);
    k_scatter<<<(N_EDGES + 255) / 256, 256, 0, stream>>>(src, dst, cursor, csr_src);

    // h0 (writes f32 h and bf16 hbfA)
    k_h0_mfma<<<NODE_BLOCKS, 256, 0, stream>>>(gat, winh, b_in, h, hbfA);

    // 12 fused Euler steps; bf16 state ping-pongs, f32 h in place
    for (int s = 0; s < STEPS; s++) {
        const unsigned short* in = (s & 1) ? hbfB : hbfA;
        unsigned short*      out = (s & 1) ? hbfA : hbfB;
        k_step<<<NODE_BLOCKS, 512, 0, stream>>>(in, h, out, offsets, csr_src, counts,
                                                w1h, b1, w2h, b2, clr);
    }
}